// Round 3
// baseline (509.647 us; speedup 1.0000x reference)
//
#include <hip/hip_runtime.h>

// NaiveLSTM: degenerate LSTM -> one batched pass.
//   gates a_g = X @ W_g + s_g  (s_g constant over b,t)
//   i,f,o = sigmoid, g = tanh; c = f*c0 + i*g; h = o*tanh(c)
// Inputs FLOAT32, outputs FLOAT32. Internals: MFMA bf16 (RNE), fp32 epilogue.
//
// R4: 512-thread blocks, wave=16 cols x 4 gates -> 2 blocks/CU (16 waves). 177us.
// R5: VALU shave at fixed occupancy (VALU ~100us chip-serial is the floor;
//     regs 96/wave cap us at 2 resident blocks, so cut instructions):
//     - v_cvt_pk_bf16_f32 replaces 7-op integer RNE pack (staging + Bf build)
//     - fmed3 clamps (1 inst vs 2)
//     - direct global dword stores; drop 17KB out-tile LDS round-trip and the
//       second barrier per iter. LDS 34304 -> 19456.

typedef __attribute__((ext_vector_type(8))) short short8;
typedef __attribute__((ext_vector_type(4))) float f32x4;
typedef __attribute__((ext_vector_type(2))) unsigned int uint2v;

#define GRID  512
#define THREADS 512
#define CHUNK 32              // rows per iteration per block
#define M_    524288          // B*T
#define ITERS 32              // (M_/CHUNK)/GRID
#define LSTR  272             // A-tile LDS row stride bytes (256 + 16 pad)
#define AB0   0
#define AB1   (32 * LSTR)     // 8704
#define SB    (2 * 32 * LSTR) // 17408: s-buffer (4 gates x 128 f32 = 2048B)
#define LDSSZ (SB + 2048)     // 19456

__device__ __forceinline__ unsigned cvtpk(float a, float b) {
    // dst.lo = bf16_rne(a), dst.hi = bf16_rne(b)
    unsigned r;
    asm("v_cvt_pk_bf16_f32 %0, %1, %2" : "=v"(r) : "v"(a), "v"(b));
    return r;
}
__device__ __forceinline__ float clamp30(float x) {
    return __builtin_amdgcn_fmed3f(x, -30.f, 30.f);
}

__global__ __launch_bounds__(THREADS, 4)
void lstm_main(const float* __restrict__ x,
               const float* __restrict__ h0,
               const float* __restrict__ c0,
               // gate order: 0=i, 1=f, 2=o, 3=g
               const float* __restrict__ wi0, const float* __restrict__ wh0,
               const float* __restrict__ bi0, const float* __restrict__ bh0,
               const float* __restrict__ wi1, const float* __restrict__ wh1,
               const float* __restrict__ bi1, const float* __restrict__ bh1,
               const float* __restrict__ wi2, const float* __restrict__ wh2,
               const float* __restrict__ bi2, const float* __restrict__ bh2,
               const float* __restrict__ wi3, const float* __restrict__ wh3,
               const float* __restrict__ bi3, const float* __restrict__ bh3,
               float* __restrict__ out)
{
    __shared__ __align__(16) char lds[LDSSZ];
    const int tid  = threadIdx.x;
    const int ww   = tid >> 6;          // wave 0..7 -> cols [16*ww, 16*ww+16)
    const int lane = tid & 63;
    const int lo   = lane & 15;
    const int hi   = lane >> 4;
    const int col  = ww * 16 + lo;      // this lane's output column

    // ---- s_g[col] = h0 . Wh_g[:,col] + bi_g[col] + bh_g[col]  (fp32, cooperative) ----
    float* sbuf = (float*)(lds + SB);
    {
        const int pc = tid & 127;
        const int g  = tid >> 7;                 // 0..3
        const float* wh = (g == 0) ? wh0 : (g == 1) ? wh1 : (g == 2) ? wh2 : wh3;
        const float* bi = (g == 0) ? bi0 : (g == 1) ? bi1 : (g == 2) ? bi2 : bi3;
        const float* bh = (g == 0) ? bh0 : (g == 1) ? bh1 : (g == 2) ? bh2 : bh3;
        float a = bi[pc] + bh[pc];
        #pragma unroll 8
        for (int k = 0; k < 128; ++k)
            a += h0[k] * wh[k * 128 + pc];
        sbuf[g * 128 + pc] = a;
    }
    __syncthreads();

    float sv[4], c0v;
    #pragma unroll
    for (int g = 0; g < 4; ++g) sv[g] = sbuf[g * 128 + col];
    c0v = c0[col];

    // ---- B fragments (bf16, RNE) in regs: layout B[k=kt*32+hi*8+j][n=col] ----
    short8 Bf[4][4];
    {
        const float* Wi[4] = { wi0, wi1, wi2, wi3 };
        #pragma unroll
        for (int g = 0; g < 4; ++g) {
            #pragma unroll
            for (int kt = 0; kt < 4; ++kt) {
                const float* wp = Wi[g] + (kt * 32 + hi * 8) * 128 + col;
                union { unsigned u[4]; short8 s; } v;
                #pragma unroll
                for (int j = 0; j < 4; ++j)
                    v.u[j] = cvtpk(wp[(2 * j) * 128], wp[(2 * j + 1) * 128]);
                Bf[g][kt] = v.s;
            }
        }
    }

    // ---- staging: chunk = 32 rows x 128 fp32 = 1024 float4; thread t takes
    //      float4 idx f = j*512+t (j=0..1): row=f>>5, cols 4*(f&31)..+3. ----
    const float4* xv4 = (const float4*)x;
    int m0 = blockIdx.x * CHUNK;
    {
        #pragma unroll
        for (int j = 0; j < 2; ++j) {
            const int f = j * 512 + tid;
            float4 v = xv4[m0 * 32 + f];
            uint2v p;
            p.x = cvtpk(v.x, v.y);
            p.y = cvtpk(v.z, v.w);
            *(uint2v*)(lds + AB0 + (f >> 5) * LSTR + (f & 31) * 8) = p;
        }
    }
    __syncthreads();

    float* hseq  = out;                       // (T,B,1,H) = 67108864 floats
    float* hlast = out + 67108864;            // (B,1,H)
    float* clast = out + 67108864 + 32768;    // (B,1,H)

    for (int it = 0; it < ITERS; ++it) {
        const char* Ab = lds + ((it & 1) ? AB1 : AB0);

        float4 pf[2];
        if (it + 1 < ITERS) {
            const int m0n = m0 + GRID * CHUNK;
            #pragma unroll
            for (int j = 0; j < 2; ++j)
                pf[j] = xv4[m0n * 32 + j * 512 + tid];
        }

        f32x4 acc[2][4];
        #pragma unroll
        for (int mt = 0; mt < 2; ++mt)
            #pragma unroll
            for (int g = 0; g < 4; ++g)
                acc[mt][g] = (f32x4){0.f, 0.f, 0.f, 0.f};

        #pragma unroll
        for (int kt = 0; kt < 4; ++kt) {
            short8 a0 = *(const short8*)(Ab + lo * LSTR + (kt * 4 + hi) * 16);
            short8 a1 = *(const short8*)(Ab + (16 + lo) * LSTR + (kt * 4 + hi) * 16);
            #pragma unroll
            for (int g = 0; g < 4; ++g) {
                acc[0][g] = __builtin_amdgcn_mfma_f32_16x16x32_bf16(a0, Bf[g][kt], acc[0][g], 0, 0, 0);
                acc[1][g] = __builtin_amdgcn_mfma_f32_16x16x32_bf16(a1, Bf[g][kt], acc[1][g], 0, 0, 0);
            }
        }

        // ---- epilogue: activations + combine; direct global dword stores ----
        const int  t0 = m0 & 2047;
        const int  b  = m0 >> 11;
        const bool lastChunk = (t0 == 2016);
        // lane's base: row t0+hi*4, column col; row stride in hseq = 32768 floats
        float* hp = hseq + (size_t)(t0 * 256 + b) * 128 + (size_t)hi * 4 * 32768 + col;
        const float K1 = 1.44269504f, K2 = 2.88539008f;
        #pragma unroll
        for (int mt = 0; mt < 2; ++mt) {
            #pragma unroll
            for (int reg = 0; reg < 4; ++reg) {
                float ai = clamp30(acc[mt][0][reg] + sv[0]);
                float af = clamp30(acc[mt][1][reg] + sv[1]);
                float ao = clamp30(acc[mt][2][reg] + sv[2]);
                float ag = clamp30(acc[mt][3][reg] + sv[3]);
                float ti = __builtin_amdgcn_exp2f(-K1 * ai);
                float tf = __builtin_amdgcn_exp2f(-K1 * af);
                float to = __builtin_amdgcn_exp2f(-K1 * ao);
                float tg = __builtin_amdgcn_exp2f(-K2 * ag);
                float fg = __builtin_amdgcn_rcpf(1.f + tf);                       // sigmoid(af)
                float ig = (1.f - tg) * __builtin_amdgcn_rcpf((1.f + ti) * (1.f + tg)); // sig(ai)*tanh(ag)
                float cv = clamp30(fg * c0v + ig);
                float tc = __builtin_amdgcn_exp2f(-K2 * cv);
                float hv = (1.f - tc) * __builtin_amdgcn_rcpf((1.f + to) * (1.f + tc)); // sig(ao)*tanh(cv)
                hp[(size_t)(mt * 16 + reg) * 32768] = hv;
                if (lastChunk && mt == 1 && reg == 3 && hi == 3) {  // row t=2047
                    hlast[b * 128 + col] = hv;
                    clast[b * 128 + col] = cv;
                }
            }
        }

        // stage next chunk into other buffer (convert + LDS write)
        if (it + 1 < ITERS) {
            char* An = lds + ((it & 1) ? AB0 : AB1);
            #pragma unroll
            for (int j = 0; j < 2; ++j) {
                const int f = j * 512 + tid;
                uint2v p;
                p.x = cvtpk(pf[j].x, pf[j].y);
                p.y = cvtpk(pf[j].z, pf[j].w);
                *(uint2v*)(An + (f >> 5) * LSTR + (f & 31) * 8) = p;
            }
        }
        __syncthreads();

        m0 += GRID * CHUNK;
    }
}

extern "C" void kernel_launch(void* const* d_in, const int* in_sizes, int n_in,
                              void* d_out, int out_size, void* d_ws, size_t ws_size,
                              hipStream_t stream) {
    (void)in_sizes; (void)n_in; (void)out_size; (void)d_ws; (void)ws_size;
    const float* x  = (const float*)d_in[0];
    const float* h0 = (const float*)d_in[1];
    const float* c0 = (const float*)d_in[2];
    // setup_inputs order: 3..6 = i (w_ii,w_hi,b_ii,b_hi), 7..10 = f, 11..14 = o, 15..18 = g
    lstm_main<<<dim3(GRID), dim3(THREADS), 0, stream>>>(
        x, h0, c0,
        (const float*)d_in[3],  (const float*)d_in[4],
        (const float*)d_in[5],  (const float*)d_in[6],
        (const float*)d_in[7],  (const float*)d_in[8],
        (const float*)d_in[9],  (const float*)d_in[10],
        (const float*)d_in[11], (const float*)d_in[12],
        (const float*)d_in[13], (const float*)d_in[14],
        (const float*)d_in[15], (const float*)d_in[16],
        (const float*)d_in[17], (const float*)d_in[18],
        (float*)d_out);
}